// Round 1
// baseline (1138.804 us; speedup 1.0000x reference)
//
#include <hip/hip_runtime.h>

#define CH   2048
#define COLS 128          // N*H = 4*32
#define WDIM 48
#define SL   (COLS*CH)    // 262144 elems per w-slice

using f32x16 = __attribute__((ext_vector_type(16))) float;
using bf16x8 = __attribute__((ext_vector_type(8))) short;

__device__ __forceinline__ short f2bf(float f) {
    union { float f; unsigned u; } v; v.f = f;
    unsigned u = v.u;
    u += 0x7fffu + ((u >> 16) & 1u);   // round-to-nearest-even
    return (short)(u >> 16);
}

// Wc bf16 from conv_w fp32 (C,C,1,9) taking [:,:,0,4]
__global__ __launch_bounds__(256) void prep_w(const float* __restrict__ cw,
                                              short* __restrict__ wcb) {
    int idx = blockIdx.x * 256 + threadIdx.x;          // o*2048 + c
    wcb[idx] = f2bf(cw[(size_t)idx * 9 + 4]);
}

// feature (N,C,H,W) -> x_t[w][col][c], col = n*32 + h
__global__ __launch_bounds__(256) void prep_x(const float* __restrict__ feat,
                                              float* __restrict__ xt) {
    int b = blockIdx.x;
    int col = b >> 5;            // 0..127
    int ct  = b & 31;            // c-tile (64 channels)
    int n = col >> 5, h = col & 31;
    int c0 = ct * 64;
    __shared__ float tile[64][49];
    int t = threadIdx.x;
    const float* base = feat + (((size_t)n * CH + c0) * 32 + h) * WDIM;
    #pragma unroll
    for (int it = 0; it < 3; ++it) {
        int id = it * 256 + t;             // 0..767
        int row = id / 12, w4 = id % 12;
        float4 v = *reinterpret_cast<const float4*>(base + (size_t)row * 1536 + w4 * 4);
        tile[row][w4*4+0] = v.x; tile[row][w4*4+1] = v.y;
        tile[row][w4*4+2] = v.z; tile[row][w4*4+3] = v.w;
    }
    __syncthreads();
    int c = t & 63, wq = t >> 6;
    #pragma unroll
    for (int it = 0; it < 12; ++it) {
        int w = it * 4 + wq;
        xt[((size_t)w * COLS + col) * CH + c0 + c] = tile[c][w];
    }
}

__global__ __launch_bounds__(256) void init0_k(const float* __restrict__ x0,
                                               float* __restrict__ fl0,
                                               short* __restrict__ fb0) {
    int i = blockIdx.x * 256 + threadIdx.x;
    float v = x0[i];
    fl0[i] = v;
    fb0[i] = f2bf(v);
}

__global__ __launch_bounds__(256) void copy_k(const float* __restrict__ s,
                                              float* __restrict__ d) {
    int i = blockIdx.x * 256 + threadIdx.x;
    d[i] = s[i];
}

// One recurrence step: out = prelu(Wc @ prev + bias) + res
// Grid 256 WGs (64 M-groups x 4 col-groups), 1024 threads = 16 waves (K-split).
__global__ __launch_bounds__(1024) void step_k(const short* __restrict__ wcb,
                                               const short* __restrict__ prevb,
                                               const float* __restrict__ res,
                                               const float* __restrict__ bias,
                                               const float* __restrict__ pa,
                                               float* __restrict__ outf,
                                               short* __restrict__ outb) {
    __shared__ float red[16][16][64];     // 64 KB: [wave][reg][lane]
    int wg = blockIdx.x;
    int mg = wg & 63, cg = wg >> 6;
    int m0 = mg * 32, n0 = cg * 32;
    int t = threadIdx.x;
    int wv = t >> 6, l = t & 63;
    int lrow = l & 31, lhalf = l >> 5;
    // A frag (32x32x16 bf16): lane l -> row l&31, k = 8*(l>>5)+j ; same for B (col role)
    const short* ap = wcb   + (size_t)(m0 + lrow) * CH + wv * 128 + 8 * lhalf;
    const short* bp = prevb + (size_t)(n0 + lrow) * CH + wv * 128 + 8 * lhalf;
    f32x16 acc = {};
    #pragma unroll
    for (int kk = 0; kk < 8; ++kk) {
        bf16x8 af = *reinterpret_cast<const bf16x8*>(ap + kk * 16);
        bf16x8 bf = *reinterpret_cast<const bf16x8*>(bp + kk * 16);
        acc = __builtin_amdgcn_mfma_f32_32x32x16_bf16(af, bf, acc, 0, 0, 0);
    }
    #pragma unroll
    for (int r = 0; r < 16; ++r) red[wv][r][l] = acc[r];
    __syncthreads();
    // 1024 threads: one output element each. C/D: col=lane&31, row=(reg&3)+8*(reg>>2)+4*(lane>>5)
    int r = t >> 6, le = t & 63;
    float s = 0.f;
    #pragma unroll
    for (int w2 = 0; w2 < 16; ++w2) s += red[w2][r][le];
    int colx = le & 31, row = (r & 3) + 8 * (r >> 2) + 4 * (le >> 5);
    int o = m0 + row;
    int gcol = n0 + colx;
    float v2 = s + bias[o];
    float a = *pa;
    v2 = (v2 >= 0.f) ? v2 : a * v2;
    v2 += res[(size_t)gcol * CH + o];
    outf[(size_t)gcol * CH + o] = v2;
    outb[(size_t)gcol * CH + o] = f2bf(v2);
}

// out_t[w][col][c] -> dout (N,C,H,W)
__global__ __launch_bounds__(256) void fin_t(const float* __restrict__ ot,
                                             float* __restrict__ dout) {
    int b = blockIdx.x;
    int col = b >> 5, ct = b & 31;
    int n = col >> 5, h = col & 31;
    int c0 = ct * 64;
    __shared__ float tile[48][65];
    int t = threadIdx.x;
    int c = t & 63, wq = t >> 6;
    #pragma unroll
    for (int it = 0; it < 12; ++it) {
        int w = it * 4 + wq;
        tile[w][c] = ot[((size_t)w * COLS + col) * CH + c0 + c];
    }
    __syncthreads();
    float* base = dout + (((size_t)n * CH + c0) * 32 + h) * WDIM;
    #pragma unroll
    for (int it = 0; it < 3; ++it) {
        int id = it * 256 + t;
        int row = id / 12, w4 = id % 12;
        float4 v;
        v.x = tile[w4*4+0][row]; v.y = tile[w4*4+1][row];
        v.z = tile[w4*4+2][row]; v.w = tile[w4*4+3][row];
        *reinterpret_cast<float4*>(base + (size_t)row * 1536 + w4 * 4) = v;
    }
}

extern "C" void kernel_launch(void* const* d_in, const int* in_sizes, int n_in,
                              void* d_out, int out_size, void* d_ws, size_t ws_size,
                              hipStream_t stream) {
    const float* feat = (const float*)d_in[0];
    const float* cw   = (const float*)d_in[1];
    const float* bias = (const float*)d_in[2];
    const float* pa   = (const float*)d_in[3];

    // fl (forward-pass fp32 states) lives in d_out: 48 slices x 1MB == out_size exactly.
    float* fl32 = (float*)d_out;

    char* ws = (char*)d_ws;
    short* wcb  = (short*)(ws);                 // 8 MB   bf16 Wc
    float* xt   = (float*)(ws + 8388608);       // 48 MB  x_t (later reused as out_t)
    short* flbf = (short*)(ws + 58720256);      // 24 MB  bf16 forward states
    short* gbf  = (short*)(ws + 83886080);      // 1 MB   bf16 backward ping-pong
    float* outt = xt;                           // alias: backward outputs (packed)

    prep_w<<<16384, 256, 0, stream>>>(cw, wcb);
    prep_x<<<4096, 256, 0, stream>>>(feat, xt);
    init0_k<<<1024, 256, 0, stream>>>(xt, fl32, flbf);   // fl[0] = x[0]

    for (int w = 1; w < 48; ++w) {
        step_k<<<256, 1024, 0, stream>>>(wcb,
                                         flbf + (size_t)(w - 1) * SL,
                                         xt   + (size_t)w * SL,
                                         bias, pa,
                                         fl32 + (size_t)w * SL,
                                         flbf + (size_t)w * SL);
    }

    // out[47] = fl[47]  (packed); then backward overwrites slices 46..0
    copy_k<<<1024, 256, 0, stream>>>(fl32 + (size_t)47 * SL, outt + (size_t)47 * SL);

    const short* prev = flbf + (size_t)47 * SL;
    for (int i = 46; i >= 0; --i) {
        short* nxt = gbf + (size_t)(i & 1) * SL;
        step_k<<<256, 1024, 0, stream>>>(wcb, prev,
                                         fl32 + (size_t)i * SL,
                                         bias, pa,
                                         outt + (size_t)i * SL,
                                         nxt);
        prev = nxt;
    }

    fin_t<<<4096, 256, 0, stream>>>(outt, (float*)d_out);
}